// Round 9
// baseline (48.169 us; speedup 1.0000x reference)
//
#include <hip/hip_runtime.h>
#include <cstdint>
#include <cstddef>

typedef __attribute__((ext_vector_type(8))) short short8;
typedef __attribute__((ext_vector_type(4))) unsigned short ushort4_t;
typedef __attribute__((ext_vector_type(16))) float f32x16;

#define NF 40
#define NK 780           // 40*39/2 pairs
#define BT 64            // batch rows per block
#define THREADS 1024     // 16 waves; grid 128; 1 block/CU (LDS = full 160 KiB pool)

__device__ __forceinline__ unsigned short f2bf(float f) {
    unsigned int u = __float_as_uint(f);
    u = (u + 0x7fffu + ((u >> 16) & 1u)) >> 16;
    return (unsigned short)u;
}
__device__ __forceinline__ float bf2f(unsigned short x) {
    return __uint_as_float(((unsigned int)x) << 16);
}

// wfrag[k][half][l][t] = bf16( W[k][ e = l&31 ][ 16*half + 8*(l>>5) + t ] )
// = A-fragment (rows e, K-dim f) for mfma_f32_32x32x16_bf16; half = f-half.
__global__ __launch_bounds__(128) void wprep_kernel(const float* __restrict__ W,
                                                    unsigned short* __restrict__ wfrag) {
    const int k = blockIdx.x, t = threadIdx.x;
    const int half = t >> 6, l = t & 63;
    const int e = l & 31;
    const int f0 = 16 * half + 8 * (l >> 5);
    const float* src = W + (size_t)k * 1024 + e * 32 + f0;
    const float4 x0 = *(const float4*)src;
    const float4 x1 = *(const float4*)(src + 4);
    short8 v;
    v[0] = (short)f2bf(x0.x); v[1] = (short)f2bf(x0.y);
    v[2] = (short)f2bf(x0.z); v[3] = (short)f2bf(x0.w);
    v[4] = (short)f2bf(x1.x); v[5] = (short)f2bf(x1.y);
    v[6] = (short)f2bf(x1.z); v[7] = (short)f2bf(x1.w);
    *(short8*)(wfrag + (size_t)k * 1024 + half * 512 + l * 8) = v;
}

// --- forced-pipeline primitives -------------------------------------------------
__device__ __forceinline__ void ld_w4(short8& r0, short8& r1, short8& r2, short8& r3,
                                      const char* addr) {
    asm volatile("global_load_dwordx4 %0, %4, off\n\t"
                 "global_load_dwordx4 %1, %4, off offset:1024\n\t"
                 "global_load_dwordx4 %2, %4, off offset:2048\n\t"
                 "global_load_dwordx4 %3, %4, off offset:3072"
                 : "=&v"(r0), "=&v"(r1), "=&v"(r2), "=&v"(r3)
                 : "v"(addr));
}
#define WAITP() do { asm volatile("s_waitcnt vmcnt(4)" ::: "memory"); \
                     __builtin_amdgcn_sched_barrier(0); } while (0)

#define LOADW2(R0, R1, R2, R3, KB)                                                      \
    {                                                                                   \
        const int kbc = (KB) > 778 ? 778 : (KB);                                        \
        ld_w4(R0, R1, R2, R3, wbase + ((size_t)kbc << 11));                             \
    }

// embT granule (field, g): g = (b + 64*fq) ^ (field&7); holds bf16 of
// emb[b0+b][field][8*fq..8*fq+7]. 4096 B per field.

// vi f32 cache for both row-halves; lane's rows: bA = b32 (half0), bB = 32+b32 (half1).
// C-layout rows e = {4h+r, 8+4h+r, 16+4h+r, 24+4h+r} -> granules b+{0,64,128,192}, byte 8*h32.
#define RELOAD_VI()                                                                     \
    {                                                                                   \
        const int i7 = ii & 7;                                                          \
        const char* ibase = embT + (ii << 12) + eoff;                                   \
        const ushort4_t a0_ = *(const ushort4_t*)(ibase + (((b32      ) ^ i7) << 4));   \
        const ushort4_t a1_ = *(const ushort4_t*)(ibase + (((b32 +  64) ^ i7) << 4));   \
        const ushort4_t a2_ = *(const ushort4_t*)(ibase + (((b32 + 128) ^ i7) << 4));   \
        const ushort4_t a3_ = *(const ushort4_t*)(ibase + (((b32 + 192) ^ i7) << 4));   \
        const ushort4_t b0_ = *(const ushort4_t*)(ibase + (((b32 +  32) ^ i7) << 4));   \
        const ushort4_t b1_ = *(const ushort4_t*)(ibase + (((b32 +  96) ^ i7) << 4));   \
        const ushort4_t b2_ = *(const ushort4_t*)(ibase + (((b32 + 160) ^ i7) << 4));   \
        const ushort4_t b3_ = *(const ushort4_t*)(ibase + (((b32 + 224) ^ i7) << 4));   \
        uA0 = bf2f(a0_[0]); uA1 = bf2f(a0_[1]); uA2  = bf2f(a0_[2]); uA3  = bf2f(a0_[3]); \
        uA4 = bf2f(a1_[0]); uA5 = bf2f(a1_[1]); uA6  = bf2f(a1_[2]); uA7  = bf2f(a1_[3]); \
        uA8 = bf2f(a2_[0]); uA9 = bf2f(a2_[1]); uA10 = bf2f(a2_[2]); uA11 = bf2f(a2_[3]); \
        uA12 = bf2f(a3_[0]); uA13 = bf2f(a3_[1]); uA14 = bf2f(a3_[2]); uA15 = bf2f(a3_[3]); \
        uB0 = bf2f(b0_[0]); uB1 = bf2f(b0_[1]); uB2  = bf2f(b0_[2]); uB3  = bf2f(b0_[3]); \
        uB4 = bf2f(b1_[0]); uB5 = bf2f(b1_[1]); uB6  = bf2f(b1_[2]); uB7  = bf2f(b1_[3]); \
        uB8 = bf2f(b2_[0]); uB9 = bf2f(b2_[1]); uB10 = bf2f(b2_[2]); uB11 = bf2f(b2_[3]); \
        uB12 = bf2f(b3_[0]); uB13 = bf2f(b3_[1]); uB14 = bf2f(b3_[2]); uB15 = bf2f(b3_[3]); \
    }

#define DOT16(T, V0, V1, V2, V3, V4, V5, V6, V7, V8, V9, V10, V11, V12, V13, V14, V15, P) \
    {                                                                                   \
        float c0 = T[0] * V0;                                                           \
        c0 = __builtin_fmaf(T[1], V1, c0);                                              \
        c0 = __builtin_fmaf(T[2], V2, c0);                                              \
        c0 = __builtin_fmaf(T[3], V3, c0);                                              \
        float c1 = T[4] * V4;                                                           \
        c1 = __builtin_fmaf(T[5], V5, c1);                                              \
        c1 = __builtin_fmaf(T[6], V6, c1);                                              \
        c1 = __builtin_fmaf(T[7], V7, c1);                                              \
        float c2 = T[8] * V8;                                                           \
        c2 = __builtin_fmaf(T[9], V9, c2);                                              \
        c2 = __builtin_fmaf(T[10], V10, c2);                                            \
        c2 = __builtin_fmaf(T[11], V11, c2);                                            \
        float c3 = T[12] * V12;                                                         \
        c3 = __builtin_fmaf(T[13], V13, c3);                                            \
        c3 = __builtin_fmaf(T[14], V14, c3);                                            \
        c3 = __builtin_fmaf(T[15], V15, c3);                                            \
        P = (c0 + c1) + (c2 + c3);                                                      \
        P += __shfl_xor(P, 32);                                                         \
    }

// one k x BOTH row-halves: 4 ds_read_b128 + 4 MFMA + 2 dot-epilogues
#define KSTEP(A0, A1, OA, OB)                                                           \
    {                                                                                   \
        const int j7 = jj & 7;                                                          \
        const char* jbase = embT + (jj << 12);                                          \
        const short8 vjA0 = *(const short8*)(jbase + (((b32 +       fh0) ^ j7) << 4));  \
        const short8 vjA1 = *(const short8*)(jbase + (((b32 + 128 + fh0) ^ j7) << 4));  \
        const short8 vjB0 = *(const short8*)(jbase + (((b32 + 32  + fh0) ^ j7) << 4));  \
        const short8 vjB1 = *(const short8*)(jbase + (((b32 + 160 + fh0) ^ j7) << 4));  \
        f32x16 tA = __builtin_amdgcn_mfma_f32_32x32x16_bf16(A0, vjA0, zacc, 0, 0, 0);   \
        tA = __builtin_amdgcn_mfma_f32_32x32x16_bf16(A1, vjA1, tA, 0, 0, 0);            \
        f32x16 tB = __builtin_amdgcn_mfma_f32_32x32x16_bf16(A0, vjB0, zacc, 0, 0, 0);   \
        tB = __builtin_amdgcn_mfma_f32_32x32x16_bf16(A1, vjB1, tB, 0, 0, 0);            \
        DOT16(tA, uA0, uA1, uA2, uA3, uA4, uA5, uA6, uA7,                               \
                  uA8, uA9, uA10, uA11, uA12, uA13, uA14, uA15, OA);                    \
        DOT16(tB, uB0, uB1, uB2, uB3, uB4, uB5, uB6, uB7,                               \
                  uB8, uB9, uB10, uB11, uB12, uB13, uB14, uB15, OB);                    \
        ++jj;                                                                           \
        if (jj == NF) { ++ii; jj = ii + 1; RELOAD_VI(); }                               \
    }

__global__ __launch_bounds__(THREADS, 4) void bil_kernel(const float* __restrict__ emb,
                                                         const unsigned short* __restrict__ wfrag,
                                                         float* __restrict__ out) {
    __shared__ __align__(16) char embT[NF * 4096];   // 163840 B = full LDS pool

    const int tid = threadIdx.x;
    const int b0 = blockIdx.x * BT;

    // --- Stage 64-row tile: coalesced 32B global reads, swizzled LDS writes (10 iters) ---
    for (int u = tid; u < BT * 160; u += THREADS) {
        const int bb = u / 160;
        const int t = u - 160 * bb;
        const int field = t >> 2;
        const int fq = t & 3;
        const float* src = emb + (size_t)(b0 + bb) * (NF * 32) + field * 32 + 8 * fq;
        const float4 x0 = *(const float4*)src;
        const float4 x1 = *(const float4*)(src + 4);
        short8 v;
        v[0] = (short)f2bf(x0.x); v[1] = (short)f2bf(x0.y);
        v[2] = (short)f2bf(x0.z); v[3] = (short)f2bf(x0.w);
        v[4] = (short)f2bf(x1.x); v[5] = (short)f2bf(x1.y);
        v[6] = (short)f2bf(x1.z); v[7] = (short)f2bf(x1.w);
        const int g = (bb + 64 * fq) ^ (field & 7);
        *(short8*)(embT + field * 4096 + g * 16) = v;
    }
    __syncthreads();

    const int ww = tid >> 6;            // wave 0..15
    const int l = tid & 63;
    const int b32 = l & 31;
    const int h32 = l >> 5;
    const int fh0 = 64 * h32;           // vj granule offset within an f-half
    const int eoff = 8 * h32;           // byte offset within vi granule

    const f32x16 zacc = {};

    // k-range per wave, multiple of 4 (48 or 52 k each)
    const int ks = 4 * ((195 * ww) >> 4);
    const int ke = 4 * ((195 * (ww + 1)) >> 4);

    int ii = 0, jj;
    {
        int kk = ks, len = 39;
        while (kk >= len) { kk -= len; ++ii; --len; }
        jj = ii + 1 + kk;
    }

    float uA0, uA1, uA2, uA3, uA4, uA5, uA6, uA7;
    float uA8, uA9, uA10, uA11, uA12, uA13, uA14, uA15;
    float uB0, uB1, uB2, uB3, uB4, uB5, uB6, uB7;
    float uB8, uB9, uB10, uB11, uB12, uB13, uB14, uB15;
    RELOAD_VI();

    const char* wbase = (const char*)wfrag + l * 16;

    short8 a0, a1, a2, a3;      // bank A: one 2-k group
    short8 c0, c1, c2, c3;      // bank B
    LOADW2(a0, a1, a2, a3, ks);

    const size_t orowoff = (size_t)(b0 + 32 * h32 + b32) * NK;  // lane's output row

    for (int kcur = ks; kcur < ke; kcur += 4) {     // 4-k superblock = 2 groups
        float oA0, oA1, oA2, oA3, oB0, oB1, oB2, oB3;
        LOADW2(c0, c1, c2, c3, kcur + 2);
        WAITP();
        KSTEP(a0, a1, oA0, oB0);
        KSTEP(a2, a3, oA1, oB1);
        LOADW2(a0, a1, a2, a3, kcur + 4);
        WAITP();
        KSTEP(c0, c1, oA2, oB2);
        KSTEP(c2, c3, oA3, oB3);
        float4 s;
        if (h32 == 0) { s.x = oA0; s.y = oA1; s.z = oA2; s.w = oA3; }
        else          { s.x = oB0; s.y = oB1; s.z = oB2; s.w = oB3; }
        *(float4*)(out + orowoff + kcur) = s;       // all 64 lanes store 16B
    }
}

extern "C" void kernel_launch(void* const* d_in, const int* in_sizes, int n_in,
                              void* d_out, int out_size, void* d_ws, size_t ws_size,
                              hipStream_t stream) {
    const float* emb = (const float*)d_in[0];
    const float* W   = (const float*)d_in[1];
    float* out = (float*)d_out;
    unsigned short* wfrag = (unsigned short*)d_ws;   // 780*2048 B = 1.6 MB scratch

    wprep_kernel<<<dim3(NK), dim3(128), 0, stream>>>(W, wfrag);
    bil_kernel<<<dim3(8192 / BT), dim3(THREADS), 0, stream>>>(emb, wfrag, out);
}